// Round 3
// baseline (292.048 us; speedup 1.0000x reference)
//
#include <hip/hip_runtime.h>
#include <hip/hip_bf16.h>

// Problem constants (reference: B=4,P=16 -> N=64, L=512, H=768, S=16)
// Dtype contract (established R1/R2): inputs fp32, d_out fp32.
//   R1 read inputs as bf16 -> NaN (fp32 mantissa halves hit bf16 NaN pattern).
//   R2 wrote bf16 out -> absmax 1.85 ~= bound of bf16-pair read as fp32.
#define NPASS 64
#define LSEQ  512
#define HDIM  768
#define NSPAN 16
#define MTOT  (NPASS*LSEQ)                     // 32768 rows
#define OFF_SENT (NPASS*HDIM)                  // 49152
#define OFF_MASK (OFF_SENT + NPASS*NSPAN*HDIM) // 835584

#define BM 128
#define BN 128
#define BK 32

typedef __bf16 bf16x8 __attribute__((ext_vector_type(8)));
typedef float  f32x4  __attribute__((ext_vector_type(4)));

__device__ inline float bf2f(unsigned short u) {
  unsigned int x = ((unsigned int)u) << 16;
  float f; __builtin_memcpy(&f, &x, 4); return f;
}
__device__ inline unsigned short f2bf(float f) {
  __hip_bfloat16 h = __float2bfloat16(f);
  unsigned short u; __builtin_memcpy(&u, &h, 2); return u;
}

// pooled = tanh(A @ W^T + bias). A: (MTOT x HDIM) fp32 row-major,
// W: (HDIM x HDIM) fp32 row-major (einsum 'nlh,oh->nlo' -> NT GEMM,
// out[m][o] = sum_h A[m][h]*W[o][h]). Output pooled: bf16 scratch.
// Staging: fp32 global -> regs -> cvt bf16 -> ds_write_b64 -> LDS [128][32] bf16.
__global__ __launch_bounds__(256) void gemm_tanh_kernel(
    const float* __restrict__ A,
    const float* __restrict__ W,
    const float* __restrict__ bias,
    unsigned short* __restrict__ pooled)
{
  __shared__ __align__(16) unsigned short As[BM*BK]; // 8 KB bf16
  __shared__ __align__(16) unsigned short Bs[BN*BK]; // 8 KB bf16

  const int tid  = threadIdx.x;
  const int wave = tid >> 6;        // 0..3
  const int lane = tid & 63;
  const int quad = lane >> 4;       // 0..3
  const int lr   = lane & 15;
  const int wm   = wave >> 1;       // wave row (0..1)
  const int wn   = wave & 1;        // wave col (0..1)
  const int tile_n = blockIdx.x * BN;
  const int tile_m = blockIdx.y * BM;

  f32x4 acc[4][4];
  #pragma unroll
  for (int i = 0; i < 4; ++i)
    #pragma unroll
    for (int j = 0; j < 4; ++j)
      acc[i][j] = (f32x4){0.f, 0.f, 0.f, 0.f};

  for (int k0 = 0; k0 < HDIM; k0 += BK) {
    // Stage A-tile and B-tile: each tile 128 rows x 32 fp32 cols = 16 KB fp32
    // -> 8 KB bf16. 1024 float4 chunks per tile; each thread handles 4 of each.
    #pragma unroll
    for (int p = 0; p < 4; ++p) {
      const int idx  = tid + p * 256;     // 0..1023
      const int row  = idx >> 3;          // 0..127
      const int col4 = idx & 7;           // float4 index within row
      const float4 a = *(const float4*)(A + (size_t)(tile_m + row) * HDIM + k0 + col4 * 4);
      const float4 b = *(const float4*)(W + (size_t)(tile_n + row) * HDIM + k0 + col4 * 4);
      uint2 ap, bp;
      ap.x = (unsigned int)f2bf(a.x) | ((unsigned int)f2bf(a.y) << 16);
      ap.y = (unsigned int)f2bf(a.z) | ((unsigned int)f2bf(a.w) << 16);
      bp.x = (unsigned int)f2bf(b.x) | ((unsigned int)f2bf(b.y) << 16);
      bp.y = (unsigned int)f2bf(b.z) | ((unsigned int)f2bf(b.w) << 16);
      *(uint2*)(As + row * BK + col4 * 4) = ap;
      *(uint2*)(Bs + row * BK + col4 * 4) = bp;
    }
    __syncthreads();

    // Fragments: A-operand A[m=lane&15][k=quad*8+j]; B-operand B[k][n=lane&15]
    // (lane lr holds W row lr = B column lr). One ds_read_b128 per fragment.
    bf16x8 af[4], bf[4];
    #pragma unroll
    for (int mt = 0; mt < 4; ++mt)
      af[mt] = *(const bf16x8*)(As + ((wm * 64 + mt * 16 + lr) * BK + quad * 8));
    #pragma unroll
    for (int nt = 0; nt < 4; ++nt)
      bf[nt] = *(const bf16x8*)(Bs + ((wn * 64 + nt * 16 + lr) * BK + quad * 8));

    #pragma unroll
    for (int mt = 0; mt < 4; ++mt)
      #pragma unroll
      for (int nt = 0; nt < 4; ++nt)
        acc[mt][nt] = __builtin_amdgcn_mfma_f32_16x16x32_bf16(
            af[mt], bf[nt], acc[mt][nt], 0, 0, 0);

    __syncthreads();
  }

  // Epilogue: C/D layout col=lane&15, row=quad*4+reg (m89/m91-verified).
  #pragma unroll
  for (int nt = 0; nt < 4; ++nt) {
    const int col = tile_n + wn * 64 + nt * 16 + lr;
    const float bv = bias[col];
    #pragma unroll
    for (int mt = 0; mt < 4; ++mt) {
      const int row0 = tile_m + wm * 64 + mt * 16 + quad * 4;
      #pragma unroll
      for (int r = 0; r < 4; ++r) {
        float v = tanhf(acc[mt][nt][r] + bv);
        pooled[(size_t)(row0 + r) * HDIM + col] = f2bf(v);
      }
    }
  }
}

// Blocks [0, N*S): span mean-pool (fp32 accumulate over bf16 pooled rows).
// Blocks [N*S, N*S+N): passage row-0 copy. Block N*S+N: zero sentence_mask.
// All outputs fp32.
__global__ __launch_bounds__(256) void pool_kernel(
    const unsigned short* __restrict__ pooled,
    const int* __restrict__ spans,
    float* __restrict__ out)
{
  const int b = blockIdx.x;
  const int t = threadIdx.x;
  if (b < NPASS * NSPAN) {
    const int st = spans[b * 2 + 0];
    const int en = spans[b * 2 + 1];
    const int n  = b / NSPAN;
    const float inv = 1.0f / (float)(en - st);
    float a0 = 0.f, a1 = 0.f, a2 = 0.f;
    for (int l = st; l < en; ++l) {
      const unsigned short* row = pooled + (size_t)(n * LSEQ + l) * HDIM;
      a0 += bf2f(row[t]);
      a1 += bf2f(row[t + 256]);
      a2 += bf2f(row[t + 512]);
    }
    float* o = out + OFF_SENT + (size_t)b * HDIM;
    o[t]       = a0 * inv;
    o[t + 256] = a1 * inv;
    o[t + 512] = a2 * inv;
  } else if (b < NPASS * NSPAN + NPASS) {
    const int n = b - NPASS * NSPAN;
    for (int c = t; c < HDIM; c += 256)
      out[(size_t)n * HDIM + c] = bf2f(pooled[(size_t)(n * LSEQ) * HDIM + c]);
  } else {
    for (int c = t; c < NPASS * NSPAN; c += 256)
      out[OFF_MASK + c] = 0.0f;
  }
}

extern "C" void kernel_launch(void* const* d_in, const int* in_sizes, int n_in,
                              void* d_out, int out_size, void* d_ws, size_t ws_size,
                              hipStream_t stream) {
  const float* hs  = (const float*)d_in[0];  // hidden_states fp32 (64,512,768)
  const float* w   = (const float*)d_in[1];  // dense_w fp32 (768,768)
  const float* bsc = (const float*)d_in[2];  // dense_b fp32 (768)
  // d_in[3] = attention_mask (unused by the reference math)
  const int* spans = (const int*)d_in[4];    // (64,16,2) int32
  float* out = (float*)d_out;
  unsigned short* pooled = (unsigned short*)d_ws;  // 32768*768*2 = 48 MB bf16

  dim3 grid(HDIM / BN, MTOT / BM);  // (6, 256) = 1536 blocks
  gemm_tanh_kernel<<<grid, dim3(256), 0, stream>>>(hs, w, bsc, pooled);
  pool_kernel<<<dim3(NPASS * NSPAN + NPASS + 1), dim3(256), 0, stream>>>(
      pooled, spans, out);
}

// Round 4
// 276.480 us; speedup vs baseline: 1.0563x; 1.0563x over previous
//
#include <hip/hip_runtime.h>
#include <hip/hip_bf16.h>

// Problem: pooled = tanh(hs @ W^T + b); out0 = pooled[:,0]; out1 = span-means;
// out2 = zeros(N,S).  N=64, L=512, H=768, S=16. Inputs fp32, d_out fp32 (R3-proven).
//
// R4 structure: memset(d_out,0) -> convert A,W to bf16 in ws (once) ->
// m97-recipe bf16 GEMM (global_load_lds width-16, zero-VALU staging) with the
// pooling fused into the epilogue as pre-scaled atomicAdds. `pooled` is never
// materialized (removes 48MB write + 46MB read + the 2nd heavy kernel).
#define NPASS 64
#define LSEQ  512
#define HDIM  768
#define NSPAN 16
#define MTOT  (NPASS*LSEQ)                     // 32768
#define OFF_SENT (NPASS*HDIM)                  // 49152
#define A_ELEMS (MTOT*HDIM)                    // 25165824
#define W_ELEMS (HDIM*HDIM)                    // 589824

#define BM 128
#define BN 128
#define BK 32

typedef __bf16 bf16x8 __attribute__((ext_vector_type(8)));
typedef float  f32x4  __attribute__((ext_vector_type(4)));

__device__ inline unsigned short f2bf(float f) {
  __hip_bfloat16 h = __float2bfloat16(f);   // RNE
  unsigned short u; __builtin_memcpy(&u, &h, 2); return u;
}

// fp32 -> bf16 one-shot convert of A (then W). 8 elems/thread, 16B stores.
__global__ __launch_bounds__(256) void convert_kernel(
    const float* __restrict__ A, const float* __restrict__ W,
    unsigned short* __restrict__ Ab, unsigned short* __restrict__ Wb)
{
  const long long i = ((long long)blockIdx.x * 256 + threadIdx.x) * 8;
  const float* src; unsigned short* dst; long long off;
  if (i < A_ELEMS) { src = A; dst = Ab; off = i; }
  else             { src = W; dst = Wb; off = i - A_ELEMS; }
  const float4 a = *(const float4*)(src + off);
  const float4 b = *(const float4*)(src + off + 4);
  union { unsigned short us[8]; uint4 v; } o;
  o.us[0]=f2bf(a.x); o.us[1]=f2bf(a.y); o.us[2]=f2bf(a.z); o.us[3]=f2bf(a.w);
  o.us[4]=f2bf(b.x); o.us[5]=f2bf(b.y); o.us[6]=f2bf(b.z); o.us[7]=f2bf(b.w);
  *(uint4*)(dst + off) = o.v;
}

// bf16 NT GEMM (m97 recipe) + fused tanh/pool epilogue.
// out[m][o] = tanh(sum_h A[m][h]*W[o][h] + bias[o]); block rows lie in one
// passage (BM=128 divides LSEQ=512).
__global__ __launch_bounds__(256) void gemm_fused_kernel(
    const unsigned short* __restrict__ Ab,
    const unsigned short* __restrict__ Wb,
    const float* __restrict__ bias,
    const int* __restrict__ spans,
    float* __restrict__ out)
{
  __shared__ __align__(16) unsigned short As[BM*BK]; // 8 KB
  __shared__ __align__(16) unsigned short Bs[BN*BK]; // 8 KB
  __shared__ int   sp_st[NSPAN], sp_en[NSPAN];
  __shared__ float inv_s[NSPAN];
  __shared__ short sid_l[BM];      // local row -> span id (-1 none)
  __shared__ float bias_s[BN];

  const int tid  = threadIdx.x;
  const int wave = tid >> 6;
  const int lane = tid & 63;
  const int quad = lane >> 4;
  const int lr   = lane & 15;
  const int wm   = wave >> 1;
  const int wn   = wave & 1;
  const int tile_n = blockIdx.x * BN;
  const int tile_m = blockIdx.y * BM;
  const int npass  = tile_m >> 9;      // passage index
  const int l0     = tile_m & 511;     // first local seq position

  // Prologue tables.
  if (tid < NSPAN) {
    const int st = spans[(npass * NSPAN + tid) * 2 + 0];
    const int en = spans[(npass * NSPAN + tid) * 2 + 1];
    sp_st[tid] = st; sp_en[tid] = en; inv_s[tid] = 1.0f / (float)(en - st);
  }
  if (tid >= 128 && tid < 128 + BN) bias_s[tid - 128] = bias[tile_n + tid - 128];
  __syncthreads();
  if (tid < BM) {
    const int l = l0 + tid;
    short s = -1;
    #pragma unroll
    for (int i = 0; i < NSPAN; ++i)
      if (l >= sp_st[i] && l < sp_en[i]) s = (short)i;
    sid_l[tid] = s;
  }
  // (sid_l/bias_s consumed only after the K-loop's syncthreads.)

  // global_load_lds: lane i writes ldsbase + i*16B. Tile row-major [128][32]
  // bf16, 64 B/row: one 1 KB segment = 16 rows; lane -> row lane/4, col (lane%4)*8.
  const int lrow = lane >> 2;
  const int lcol = (lane & 3) * 8;

  f32x4 acc[4][4];
  #pragma unroll
  for (int i = 0; i < 4; ++i)
    #pragma unroll
    for (int j = 0; j < 4; ++j)
      acc[i][j] = (f32x4){0.f, 0.f, 0.f, 0.f};

  for (int k0 = 0; k0 < HDIM; k0 += BK) {
    #pragma unroll
    for (int j = 0; j < 4; ++j) {
      const int seg = wave * 4 + j;        // wave-uniform 0..15
      if (seg < 8) {
        const unsigned short* g =
            Ab + (size_t)(tile_m + seg * 16 + lrow) * HDIM + (k0 + lcol);
        __builtin_amdgcn_global_load_lds(
            (const __attribute__((address_space(1))) void*)g,
            (__attribute__((address_space(3))) void*)(As + seg * 512),
            16, 0, 0);
      } else {
        const int s2 = seg - 8;
        const unsigned short* g =
            Wb + (size_t)(tile_n + s2 * 16 + lrow) * HDIM + (k0 + lcol);
        __builtin_amdgcn_global_load_lds(
            (const __attribute__((address_space(1))) void*)g,
            (__attribute__((address_space(3))) void*)(Bs + s2 * 512),
            16, 0, 0);
      }
    }
    __syncthreads();  // drains vmcnt(0): staging + (first iter) tables done

    bf16x8 af[4], bf[4];
    #pragma unroll
    for (int mt = 0; mt < 4; ++mt)
      af[mt] = *(const bf16x8*)(As + ((wm * 64 + mt * 16 + lr) * BK + quad * 8));
    #pragma unroll
    for (int nt = 0; nt < 4; ++nt)
      bf[nt] = *(const bf16x8*)(Bs + ((wn * 64 + nt * 16 + lr) * BK + quad * 8));

    #pragma unroll
    for (int mt = 0; mt < 4; ++mt)
      #pragma unroll
      for (int nt = 0; nt < 4; ++nt)
        acc[mt][nt] = __builtin_amdgcn_mfma_f32_16x16x32_bf16(
            af[mt], bf[nt], acc[mt][nt], 0, 0, 0);

    __syncthreads();
  }

  // Epilogue. C/D layout: col=lane&15, row=quad*4+reg (R3-validated).
  // Sentence means: atomicAdd of run-merged tanh sums pre-scaled by 1/count
  // into pre-zeroed out. Passage row 0: direct store.
  #pragma unroll
  for (int nt = 0; nt < 4; ++nt) {
    const int lcolo = wn * 64 + nt * 16 + lr;       // 0..127
    const int col   = tile_n + lcolo;
    const float bv  = bias_s[lcolo];
    float* sent_col = out + OFF_SENT + (size_t)(npass * NSPAN) * HDIM + col;
    #pragma unroll
    for (int mt = 0; mt < 4; ++mt) {
      const int rowbase = wm * 64 + mt * 16 + quad * 4;  // local row
      int prev = -1; float run = 0.f;
      #pragma unroll
      for (int r = 0; r < 4; ++r) {
        const int lrw = rowbase + r;
        const float v = tanhf(acc[mt][nt][r] + bv);
        if (l0 == 0 && lrw == 0) out[(size_t)npass * HDIM + col] = v;
        const int s = sid_l[lrw];
        if (s != prev) {
          if (prev >= 0) unsafeAtomicAdd(sent_col + (size_t)prev * HDIM, run * inv_s[prev]);
          prev = s; run = 0.f;
        }
        run += v;
      }
      if (prev >= 0) unsafeAtomicAdd(sent_col + (size_t)prev * HDIM, run * inv_s[prev]);
    }
  }
}

extern "C" void kernel_launch(void* const* d_in, const int* in_sizes, int n_in,
                              void* d_out, int out_size, void* d_ws, size_t ws_size,
                              hipStream_t stream) {
  const float* hs  = (const float*)d_in[0];  // (64,512,768) fp32
  const float* w   = (const float*)d_in[1];  // (768,768) fp32
  const float* bsc = (const float*)d_in[2];  // (768,) fp32
  // d_in[3] attention_mask unused
  const int* spans = (const int*)d_in[4];    // (64,16,2) int32
  float* out = (float*)d_out;

  unsigned short* Ab = (unsigned short*)d_ws;            // 50,331,648 B
  unsigned short* Wb = Ab + A_ELEMS;                     // +1,179,648 B = 51.5 MB

  // Zero all outputs (sentence region is accumulated into; mask stays 0).
  hipMemsetAsync(d_out, 0, (size_t)out_size * sizeof(float), stream);

  convert_kernel<<<dim3((A_ELEMS + W_ELEMS) / 8 / 256), dim3(256), 0, stream>>>(
      hs, w, Ab, Wb);

  dim3 grid(HDIM / BN, MTOT / BM);  // (6,256) = 1536 blocks
  gemm_fused_kernel<<<grid, dim3(256), 0, stream>>>(Ab, Wb, bsc, spans, out);
}

// Round 5
// 267.422 us; speedup vs baseline: 1.0921x; 1.0339x over previous
//
#include <hip/hip_runtime.h>
#include <hip/hip_bf16.h>

// Problem: pooled = tanh(hs @ W^T + b); out0 = pooled[:,0]; out1 = span-means;
// out2 = zeros(N,S).  N=64, L=512, H=768, S=16. Inputs fp32, d_out fp32.
//
// R5: R4 structure + (1) double-buffered LDS with one barrier/iter and
// prefetch-distance-1 (the vmcnt(0) drain at the barrier now waits on loads
// issued a full compute-phase earlier), (2) grid transposed to (M fast, N slow)
// so the 6 blocks sharing an A-tile land on the SAME XCD (round-robin % 8),
// (3) exp-based tanh in the epilogue.
#define NPASS 64
#define LSEQ  512
#define HDIM  768
#define NSPAN 16
#define MTOT  (NPASS*LSEQ)                     // 32768
#define OFF_SENT (NPASS*HDIM)                  // 49152
#define A_ELEMS (MTOT*HDIM)                    // 25165824
#define W_ELEMS (HDIM*HDIM)                    // 589824

#define BM 128
#define BN 128
#define BK 32
#define NK (HDIM/BK)                           // 24 K-iterations

typedef __bf16 bf16x8 __attribute__((ext_vector_type(8)));
typedef float  f32x4  __attribute__((ext_vector_type(4)));

__device__ inline unsigned short f2bf(float f) {
  __hip_bfloat16 h = __float2bfloat16(f);   // RNE
  unsigned short u; __builtin_memcpy(&u, &h, 2); return u;
}

// tanh via v_exp_f32: ~7 VALU ops vs ~25 for libm tanhf. |err| < 1e-6 rel,
// far inside the 2% threshold (bf16 input rounding dominates at 6e-3).
__device__ inline float fast_tanh(float x) {
  const float ax = fabsf(x);
  const float t  = __expf(-2.0f * ax);                  // v_exp_f32 path
  const float r  = (1.0f - t) * __builtin_amdgcn_rcpf(1.0f + t);
  return copysignf(r, x);
}

// fp32 -> bf16 one-shot convert of A then W. 8 elems/thread, 16B stores.
__global__ __launch_bounds__(256) void convert_kernel(
    const float* __restrict__ A, const float* __restrict__ W,
    unsigned short* __restrict__ Ab, unsigned short* __restrict__ Wb)
{
  const long long i = ((long long)blockIdx.x * 256 + threadIdx.x) * 8;
  const float* src; unsigned short* dst; long long off;
  if (i < A_ELEMS) { src = A; dst = Ab; off = i; }
  else             { src = W; dst = Wb; off = i - A_ELEMS; }
  const float4 a = *(const float4*)(src + off);
  const float4 b = *(const float4*)(src + off + 4);
  union { unsigned short us[8]; uint4 v; } o;
  o.us[0]=f2bf(a.x); o.us[1]=f2bf(a.y); o.us[2]=f2bf(a.z); o.us[3]=f2bf(a.w);
  o.us[4]=f2bf(b.x); o.us[5]=f2bf(b.y); o.us[6]=f2bf(b.z); o.us[7]=f2bf(b.w);
  *(uint4*)(dst + off) = o.v;
}

// bf16 NT GEMM + fused tanh/pool epilogue. Grid: x = M-tile (256), y = N-tile (6).
__global__ __launch_bounds__(256) void gemm_fused_kernel(
    const unsigned short* __restrict__ Ab,
    const unsigned short* __restrict__ Wb,
    const float* __restrict__ bias,
    const int* __restrict__ spans,
    float* __restrict__ out)
{
  __shared__ __align__(16) unsigned short As[2][BM*BK]; // 2 x 8 KB
  __shared__ __align__(16) unsigned short Bs[2][BN*BK]; // 2 x 8 KB
  __shared__ int   sp_st[NSPAN], sp_en[NSPAN];
  __shared__ float inv_s[NSPAN];
  __shared__ short sid_l[BM];      // local row -> span id (-1 none)
  __shared__ float bias_s[BN];

  const int tid  = threadIdx.x;
  const int wave = tid >> 6;
  const int lane = tid & 63;
  const int quad = lane >> 4;
  const int lr   = lane & 15;
  const int wm   = wave >> 1;
  const int wn   = wave & 1;
  const int tile_m = blockIdx.x * BM;   // M fast => same-A blocks same XCD
  const int tile_n = blockIdx.y * BN;
  const int npass  = tile_m >> 9;       // passage index
  const int l0     = tile_m & 511;      // first local seq position

  // global_load_lds: lane i writes ldsbase + i*16B. Tile row-major [128][32]
  // bf16, 64 B/row: one 1 KB segment = 16 rows; lane -> row lane/4, col (lane%4)*8.
  const int lrow = lane >> 2;
  const int lcol = (lane & 3) * 8;

  // Stage K-slice k into buffer buf. Each wave issues 4 x 1KB segments.
  auto stage = [&](int k, int buf) {
    const int k0 = k * BK;
    #pragma unroll
    for (int j = 0; j < 4; ++j) {
      const int seg = wave * 4 + j;        // wave-uniform 0..15
      if (seg < 8) {
        const unsigned short* g =
            Ab + (size_t)(tile_m + seg * 16 + lrow) * HDIM + (k0 + lcol);
        __builtin_amdgcn_global_load_lds(
            (const __attribute__((address_space(1))) void*)g,
            (__attribute__((address_space(3))) void*)(As[buf] + seg * 512),
            16, 0, 0);
      } else {
        const int s2 = seg - 8;
        const unsigned short* g =
            Wb + (size_t)(tile_n + s2 * 16 + lrow) * HDIM + (k0 + lcol);
        __builtin_amdgcn_global_load_lds(
            (const __attribute__((address_space(1))) void*)g,
            (__attribute__((address_space(3))) void*)(Bs[buf] + s2 * 512),
            16, 0, 0);
      }
    }
  };

  // Prologue: stage slice 0, fill tables, one barrier covers both.
  stage(0, 0);
  if (tid < NSPAN) {
    const int st = spans[(npass * NSPAN + tid) * 2 + 0];
    const int en = spans[(npass * NSPAN + tid) * 2 + 1];
    sp_st[tid] = st; sp_en[tid] = en; inv_s[tid] = 1.0f / (float)(en - st);
  }
  if (tid >= 128 && tid < 128 + BN) bias_s[tid - 128] = bias[tile_n + tid - 128];
  __syncthreads();
  // sid_l written here, first read in epilogue (after many barriers).
  if (tid < BM) {
    const int l = l0 + tid;
    short s = -1;
    #pragma unroll
    for (int i = 0; i < NSPAN; ++i)
      if (l >= sp_st[i] && l < sp_en[i]) s = (short)i;
    sid_l[tid] = s;
  }

  f32x4 acc[4][4];
  #pragma unroll
  for (int i = 0; i < 4; ++i)
    #pragma unroll
    for (int j = 0; j < 4; ++j)
      acc[i][j] = (f32x4){0.f, 0.f, 0.f, 0.f};

  for (int k = 0; k < NK; ++k) {
    const int cur = k & 1;
    if (k + 1 < NK) stage(k + 1, cur ^ 1);   // prefetch next slice first

    // Fragments: A-operand A[m=lane&15][k=quad*8+j]; B-operand B[k][n=lane&15].
    bf16x8 af[4], bf[4];
    #pragma unroll
    for (int mt = 0; mt < 4; ++mt)
      af[mt] = *(const bf16x8*)(As[cur] + ((wm * 64 + mt * 16 + lr) * BK + quad * 8));
    #pragma unroll
    for (int nt = 0; nt < 4; ++nt)
      bf[nt] = *(const bf16x8*)(Bs[cur] + ((wn * 64 + nt * 16 + lr) * BK + quad * 8));

    #pragma unroll
    for (int mt = 0; mt < 4; ++mt)
      #pragma unroll
      for (int nt = 0; nt < 4; ++nt)
        acc[mt][nt] = __builtin_amdgcn_mfma_f32_16x16x32_bf16(
            af[mt], bf[nt], acc[mt][nt], 0, 0, 0);

    // One barrier/iter: (a) everyone done reading buf cur before it's
    // overwritten at k+1; (b) compiler's vmcnt(0) drain covers the prefetch —
    // which has had the whole compute phase to complete.
    __syncthreads();
  }

  // Epilogue. C/D layout: col=lane&15, row=quad*4+reg (R3/R4-validated).
  // Sentence means: run-merged, pre-scaled atomic adds into pre-zeroed out.
  #pragma unroll
  for (int nt = 0; nt < 4; ++nt) {
    const int lcolo = wn * 64 + nt * 16 + lr;       // 0..127
    const int col   = tile_n + lcolo;
    const float bv  = bias_s[lcolo];
    float* sent_col = out + OFF_SENT + (size_t)(npass * NSPAN) * HDIM + col;
    #pragma unroll
    for (int mt = 0; mt < 4; ++mt) {
      const int rowbase = wm * 64 + mt * 16 + quad * 4;  // local row
      int prev = -1; float run = 0.f;
      #pragma unroll
      for (int r = 0; r < 4; ++r) {
        const int lrw = rowbase + r;
        const float v = fast_tanh(acc[mt][nt][r] + bv);
        if (l0 == 0 && lrw == 0) out[(size_t)npass * HDIM + col] = v;
        const int s = sid_l[lrw];
        if (s != prev) {
          if (prev >= 0) unsafeAtomicAdd(sent_col + (size_t)prev * HDIM, run * inv_s[prev]);
          prev = s; run = 0.f;
        }
        run += v;
      }
      if (prev >= 0) unsafeAtomicAdd(sent_col + (size_t)prev * HDIM, run * inv_s[prev]);
    }
  }
}

extern "C" void kernel_launch(void* const* d_in, const int* in_sizes, int n_in,
                              void* d_out, int out_size, void* d_ws, size_t ws_size,
                              hipStream_t stream) {
  const float* hs  = (const float*)d_in[0];  // (64,512,768) fp32
  const float* w   = (const float*)d_in[1];  // (768,768) fp32
  const float* bsc = (const float*)d_in[2];  // (768,) fp32
  // d_in[3] attention_mask unused
  const int* spans = (const int*)d_in[4];    // (64,16,2) int32
  float* out = (float*)d_out;

  unsigned short* Ab = (unsigned short*)d_ws;            // 50,331,648 B
  unsigned short* Wb = Ab + A_ELEMS;                     // +1,179,648 B = 51.5 MB

  hipMemsetAsync(d_out, 0, (size_t)out_size * sizeof(float), stream);

  convert_kernel<<<dim3((A_ELEMS + W_ELEMS) / 8 / 256), dim3(256), 0, stream>>>(
      hs, w, Ab, Wb);

  dim3 grid(MTOT / BM, HDIM / BN);  // (256, 6): M fast -> A-tile sharers co-XCD
  gemm_fused_kernel<<<grid, dim3(256), 0, stream>>>(Ab, Wb, bsc, spans, out);
}